// Round 16
// baseline (326.343 us; speedup 1.0000x reference)
//
#include <hip/hip_runtime.h>
#include <math.h>

#define HW 4096   // H*W = 64*64; B=4, C=64, H=W=64, L=4096

typedef short bf16x8 __attribute__((ext_vector_type(8)));
typedef float floatx4 __attribute__((ext_vector_type(4)));
typedef unsigned short u16x8 __attribute__((ext_vector_type(8)));

__device__ __forceinline__ unsigned short f2bf_rne(float x) {
    unsigned int u = __float_as_uint(x);
    unsigned int r = (u + 0x7FFFu + ((u >> 16) & 1u)) >> 16;
    return (unsigned short)r;
}
__device__ __forceinline__ float bf2f(unsigned short h) {
    return __uint_as_float(((unsigned int)h) << 16);
}

// async global->LDS, 16 B per lane; LDS dest is wave-uniform base + lane*16.
__device__ __forceinline__ void gload_lds16(const void* gptr, void* lptr) {
    auto g = (const __attribute__((address_space(1))) unsigned int*)(unsigned long long)(gptr);
    auto l = (__attribute__((address_space(3))) unsigned int*)(unsigned int)(unsigned long long)(lptr);
    __builtin_amdgcn_global_load_lds(g, l, 16, 0, 0);
}

// ---------------- prep: z=0 Q / z=1 K: split fp32 -> bf16 (hi,lo), transpose
// to [p][c], fused per-pixel squared norms. Row layout (192 shorts):
//   Aq[b][p] = [Qh | UNINIT | Ql],  Bq[b][p] = [Kh | Kl | UNINIT]
// (readers use only A slices {0,2} / B slices {0,1}).
// z=2: transpose V -> VT[b][p][c] (f32) so gatherT reads channels contiguous.
__global__ __launch_bounds__(256)
void prep_kernel(const float* __restrict__ Q, const float* __restrict__ K,
                 const float* __restrict__ V,
                 unsigned short* __restrict__ Aq, unsigned short* __restrict__ Bq,
                 float* __restrict__ VT,
                 float* __restrict__ pix2q, float* __restrict__ pix2k) {
    __shared__ float sT[64][65];
    const int tid = threadIdx.x;
    const int p0 = blockIdx.x * 64;
    const int b = blockIdx.y;
    const int which = blockIdx.z;            // 0=Q, 1=K, 2=V
    const float* __restrict__ src = (which == 0) ? Q : ((which == 1) ? K : V);

#pragma unroll
    for (int it = 0; it < 16; ++it) {
        int idx = it * 256 + tid;
        int c = idx >> 6, x = idx & 63;
        sT[c][x] = src[((size_t)b * 64 + c) * HW + p0 + x];
    }
    __syncthreads();
    const int pp = tid >> 2, qt = tid & 3;

    if (which == 2) {                        // V: pure f32 transpose
        float* dst = VT + ((size_t)b * 4096 + p0 + pp) * 64 + qt * 16;
#pragma unroll
        for (int j = 0; j < 4; ++j) {
            float4 v = make_float4(sT[qt * 16 + 4 * j + 0][pp], sT[qt * 16 + 4 * j + 1][pp],
                                   sT[qt * 16 + 4 * j + 2][pp], sT[qt * 16 + 4 * j + 3][pp]);
            *(float4*)(dst + 4 * j) = v;
        }
        return;
    }

    const int isK = which;
    unsigned short* __restrict__ dst = isK ? Bq : Aq;
    float* __restrict__ pix2 = isK ? pix2k : pix2q;
    const size_t base = ((size_t)b * 4096 + p0 + pp) * 192;
    {
        float sq = 0.f;
        u16x8 hv[2], lv[2];
#pragma unroll
        for (int g = 0; g < 2; ++g)
#pragma unroll
            for (int j = 0; j < 8; ++j) {
                int c = qt * 16 + g * 8 + j;
                float x = sT[c][pp];
                sq = fmaf(x, x, sq);
                unsigned short h = f2bf_rne(x);
                hv[g][j] = h;
                lv[g][j] = f2bf_rne(x - bf2f(h));
            }
        sq += __shfl_xor(sq, 1, 64);
        sq += __shfl_xor(sq, 2, 64);
        if (qt == 0) pix2[(b << 12) + p0 + pp] = sq;
#pragma unroll
        for (int g = 0; g < 2; ++g) {
            int co = qt * 16 + g * 8;
            *(u16x8*)(dst + base + co)                     = hv[g];  // hi slice
            *(u16x8*)(dst + base + (isK ? 64 : 128) + co)  = lv[g];  // lo slice
        }
    }
}

// ---------------- fused MFMA GEMM (K=576: y-3sum in K) + x-3sum + argmax -----
// 128x128 tile, 8 waves (512 thr), wave tile 64(q) x 32(k): acc = 32 regs.
// K-BATCHING: each block = (b, qt, kQ) processes 8 consecutive k-tiles
// (k = kQ*1024 .. +1024) with running per-strip (bv,ba) in registers; one
// final cross-wave reduce with value-tie -> smaller-index tie-break (exact
// first-occurrence argmax since per-strip maxima span tiles).
// Partial slots per q: 4 (vs 32).  512 blocks -> 2 blocks/CU preserved.
// Inner loop = R13's proven schedule: 3 mega-steps/tile, all 12 frag
// ds_reads up front per kk, 16x16x32 MFMA (32x32 is 4-way bank-conflicted
// with the gload_lds-linear layout -- R15 falsified).
// Rings: A 5 slots {Ah0@0,Ah1@1,Ah2@4,Ah3@2; Al0@2,Al1@3,Al2@0,Al3@3},
//        B 5 slots {Bh0@0,Bh1@1,Bh2@4,Bh3@2; Bl0@2,Bl1@3,Bl2@0,Bl3@3}.
// Counted-vmcnt schedule identical to R12/R13 (hand-verified).  Per-tile
// epilogue pix2k loads drain via compiler waits before next tile's PBARs.
#define WAITV(n_) asm volatile("s_waitcnt vmcnt(" #n_ ")" ::: "memory")
#define PBAR(n_) do { WAITV(n_); __builtin_amdgcn_s_barrier(); \
                      asm volatile("" ::: "memory"); } while (0)
#define SB do { __builtin_amdgcn_s_barrier(); asm volatile("" ::: "memory"); } while (0)

#define ISSUE_A(c_, sg_, slot_) \
    gload_lds16(agb + (size_t)((c_) * 64 + rr) * 384 + (sg_) * 128 + G16, \
                smem + (slot_) * 8192 + t16)
#define ISSUE_B(c_, sg_, slot_) \
    gload_lds16(bgb + (size_t)((c_) * 64 + rr) * 384 + (sg_) * 128 + G16, \
                smemB + (slot_) * 8192 + t16)

#define GISS_A(c_, sg_, slot_) do { \
    uint4 v_ = make_uint4(0u, 0u, 0u, 0u); \
    if ((unsigned)(arow + (c_) * 64 + rr) < 4096u) \
        v_ = *(const uint4*)(agb + (ptrdiff_t)((c_) * 64 + rr) * 384 + (sg_) * 128 + G16); \
    *(uint4*)(smem + (slot_) * 8192 + t16) = v_; \
} while (0)
#define GISS_B(c_, sg_, slot_) do { \
    uint4 v_ = make_uint4(0u, 0u, 0u, 0u); \
    if ((unsigned)(brow + (c_) * 64 + rr) < 4096u) \
        v_ = *(const uint4*)(bgb + (ptrdiff_t)((c_) * 64 + rr) * 384 + (sg_) * 128 + G16); \
    *(uint4*)(smemB + (slot_) * 8192 + t16) = v_; \
} while (0)

#define MM8(af_, bf_) do { \
    _Pragma("unroll") \
    for (int mt_ = 0; mt_ < 4; ++mt_) \
        _Pragma("unroll") \
        for (int nt_ = 0; nt_ < 2; ++nt_) \
            acc[mt_][nt_] = __builtin_amdgcn_mfma_f32_16x16x32_bf16( \
                (af_)[mt_], (bf_)[nt_], acc[mt_][nt_], 0, 0, 0); \
} while (0)

#define DY_MEGA(dy_) do { \
    const char* AhS_ = smem + ahS[wm + (dy_)] * 8192 + rowB; \
    const char* AlS_ = smem + alS[wm + (dy_)] * 8192 + rowB; \
    const char* BhS_ = smemB + bhS[wnC + (dy_)] * 8192 + rowBB; \
    const char* BlS_ = smemB + blS[wnC + (dy_)] * 8192 + rowBB; \
    _Pragma("unroll") \
    for (int kk = 0; kk < 2; ++kk) { \
        const int pk_ = kk ? posK1 : posK0; \
        bf16x8 afc[4], bfc[2], bl2[2], al4[4]; \
        _Pragma("unroll") \
        for (int mt = 0; mt < 4; ++mt) \
            afc[mt] = *(const bf16x8*)(AhS_ + mt * 2048 + pk_); \
        _Pragma("unroll") \
        for (int nt = 0; nt < 2; ++nt) \
            bfc[nt] = *(const bf16x8*)(BhS_ + nt * 2048 + pk_); \
        _Pragma("unroll") \
        for (int nt = 0; nt < 2; ++nt) \
            bl2[nt] = *(const bf16x8*)(BlS_ + nt * 2048 + pk_); \
        _Pragma("unroll") \
        for (int mt = 0; mt < 4; ++mt) \
            al4[mt] = *(const bf16x8*)(AlS_ + mt * 2048 + pk_); \
        __builtin_amdgcn_s_setprio(1); \
        MM8(afc, bfc); \
        MM8(afc, bl2); \
        MM8(al4, bfc); \
        __builtin_amdgcn_s_setprio(0); \
    } \
} while (0)

__global__ __launch_bounds__(512, 4)
void gemm_fused_kernel(const unsigned short* __restrict__ Aq, const unsigned short* __restrict__ Bq,
                       const float* __restrict__ pix2k,
                       float* __restrict__ part_val, int* __restrict__ part_arg) {
    __shared__ __align__(16) char smem[81920];   // A 5x8K | B 5x8K; epilogue aliases A region
    char* const smemB = smem + 40960;
    const int tid = threadIdx.x;
    const int lane = tid & 63, wid = tid >> 6;
    const int m15 = lane & 15, quad = lane >> 4;
    const int wm = wid & 1;                  // q half (64 rows)
    const int wn2 = wid >> 1;                // k quarter (32 cols), 0..3
    const int wnC = wn2 >> 1, wnF = wn2 & 1; // B chunk half / frag pair
    // chunk -> slot maps (see header comment)
    const int ahS[4] = {0, 1, 4, 2};
    const int alS[4] = {2, 3, 0, 3};
    const int bhS[4] = {0, 1, 4, 2};
    const int blS[4] = {2, 3, 0, 3};
    // XCD swizzle: per-b 128 wgs; block = (qt 32, kQ 4)
    const int f = blockIdx.x;
    const int o = ((f & 7) << 4) + (f >> 3);
    const int qt = o >> 2, kQ = o & 3;
    const int q0 = qt << 7;
    const int b = blockIdx.y;
    const int arow = q0 - 64;
    const char* agb = (const char*)(Aq + (size_t)b * 4096 * 192) + (ptrdiff_t)arow * 384;
    const char* Bqb = (const char*)(Bq + (size_t)b * 4096 * 192);
    const bool aInt = (q0 >= 64) && (q0 <= 4096 - 192);

    // staging: 512 thr x 16 B = one 8 KB chunk per issue (1 gload/thread)
    const int rr = tid >> 3;
    const int G16 = ((tid & 7) ^ (rr & 7)) * 16;
    const int t16 = tid * 16;
    // fragment-read offsets (row&7 == m15&7 for all frag rows)
    const int rowB = m15 * 128;
    const int rowBB = (wnF * 32 + m15) * 128;
    const int posK0 = (quad ^ (m15 & 7)) * 16;
    const int posK1 = ((4 + quad) ^ (m15 & 7)) * 16;

    // epilogue views (A region; dead outside epilogue phases)
    float* Csh = (float*)smem;               // [64][133] = 34048 B
    float* bvs = (float*)(smem + 34816);     // [8][64]
    int*   bas = (int*)(smem + 36864);       // [8][64]
    float* Lrnk = (float*)(smem + 38912);    // [128]
    const int q_l = tid & 63;
    const int qr = tid >> 6;                 // k-eighth (0..7), one per wave
    const int c0 = qr * 16;
    const float4 zero4 = make_float4(0.f, 0.f, 0.f, 0.f);

    float bvr[2] = {-INFINITY, -INFINITY};   // running max per h-phase
    int   bar[2] = {0, 0};

    for (int t = 0; t < 8; ++t) {            // 8 k-tiles, ascending k
        const int k0 = (kQ << 10) + (t << 7);
        const int brow = k0 - 64;
        const char* bgb = Bqb + (ptrdiff_t)brow * 384;
        const bool bInt = (k0 >= 64) && (k0 <= 4096 - 192);

        floatx4 acc[4][2];
#pragma unroll
        for (int i = 0; i < 4; ++i)
#pragma unroll
            for (int j = 0; j < 2; ++j) acc[i][j] = (floatx4)0.f;

        if (aInt && bInt) {
            // prologue (10 chunks): Ah0@0 Ah1@1 Bh0@0 Bh1@1 Al0@2 Al1@3
            // Bl0@2 Bl1@3 Ah2@4 Bh2@4
            ISSUE_A(0, 0, 0); ISSUE_A(1, 0, 1); ISSUE_B(0, 0, 0); ISSUE_B(1, 0, 1);
            ISSUE_A(0, 2, 2); ISSUE_A(1, 2, 3); ISSUE_B(0, 1, 2); ISSUE_B(1, 1, 3);
            ISSUE_A(2, 0, 4); ISSUE_B(2, 0, 4);
            PBAR(2);                 // retire first 8 = dy0 working set
            DY_MEGA(0);
            SB;                      // dy0 readers done -> slots 0,2 free
            ISSUE_A(2, 2, 0);        // Al2 -> A slot 0
            ISSUE_B(2, 1, 0);        // Bl2 -> B slot 0
            ISSUE_A(3, 0, 2);        // Ah3 -> A slot 2
            ISSUE_B(3, 0, 2);        // Bh3 -> B slot 2
            PBAR(2);                 // retire Ah2,Bh2,Al2,Bl2 (Ah3,Bh3 in flight)
            DY_MEGA(1);
            SB;                      // dy1 readers done -> slots 3 free
            ISSUE_A(3, 2, 3);        // Al3 -> A slot 3
            ISSUE_B(3, 1, 3);        // Bl3 -> B slot 3
            PBAR(0);                 // retire Ah3,Bh3,Al3,Bl3
            DY_MEGA(2);
        } else {
            // guarded boundary path: same slots, predicated uint4 + ds_write
            GISS_A(0, 0, 0); GISS_A(1, 0, 1); GISS_B(0, 0, 0); GISS_B(1, 0, 1);
            GISS_A(0, 2, 2); GISS_A(1, 2, 3); GISS_B(0, 1, 2); GISS_B(1, 1, 3);
            GISS_A(2, 0, 4); GISS_B(2, 0, 4);
            __syncthreads();
            DY_MEGA(0);
            __syncthreads();
            GISS_A(2, 2, 0); GISS_B(2, 1, 0); GISS_A(3, 0, 2); GISS_B(3, 0, 2);
            __syncthreads();
            DY_MEGA(1);
            __syncthreads();
            GISS_A(3, 2, 3); GISS_B(3, 1, 3);
            __syncthreads();
            DY_MEGA(2);
        }
        __syncthreads();   // rings dead before epilogue overwrites

        // ---- per-tile epilogue: Lrnk (3x3 pix2k box); two 64-row phases;
        // x-3sum + argmax over this 128-k tile into running bvr/bar ----
        if (tid < 128) {
            int k = k0 + tid;
            int py = k >> 6, px = k & 63;
            float sk = 0.f;
            for (int dy = -1; dy <= 1; ++dy)
                for (int dx = -1; dx <= 1; ++dx) {
                    int yy = py + dy, xx = px + dx;
                    if ((unsigned)yy < 64u && (unsigned)xx < 64u)
                        sk += pix2k[(b << 12) + (yy << 6) + xx];
                }
            Lrnk[tid] = 1.f / fmaxf(sqrtf(sk), 1e-12f);
        }
#pragma unroll
        for (int h = 0; h < 2; ++h) {
            if (h) __syncthreads();          // phase-0 readers done before overwrite
            if (wm == h) {
#pragma unroll
                for (int mt = 0; mt < 4; ++mt)
#pragma unroll
                    for (int nt = 0; nt < 2; ++nt)
#pragma unroll
                        for (int j = 0; j < 4; ++j)
                            Csh[(mt * 16 + quad * 4 + j) * 133 + (wn2 << 5) + nt * 16 + m15] =
                                acc[mt][nt][j];
            }
            __syncthreads();                 // also orders Lrnk writes (h==0)

            const bool qm = q_l > 0;         // qx>0: diag- allowed
            const bool qp = q_l < 63;        // qx<63: diag+ allowed
            const float* rC = Csh + q_l * 133;
            const float* rM = Csh + (q_l - 1) * 133;
            const float* rP = Csh + (q_l + 1) * 133;
            float4 prevm = (qm && c0 > 0) ? *(const float4*)&rM[c0 - 4] : zero4;
            float4 rpj   = qp ? *(const float4*)&rP[c0] : zero4;
            float bv = bvr[h];
            int ba = bar[h];
#pragma unroll
            for (int j = 0; j < 4; ++j) {
                int c = c0 + 4 * j;
                float4 cen = *(const float4*)&rC[c];
                float4 rm4 = qm ? *(const float4*)&rM[c] : zero4;
                float4 rp1 = (qp && (c + 4) < 128) ? *(const float4*)&rP[c + 4] : zero4;
                float4 o4;
                o4.x = cen.x + (((c & 63) != 0) ? prevm.w : 0.f) + rpj.y;
                o4.y = cen.y + rm4.x + rpj.z;
                o4.z = cen.z + rm4.y + rpj.w;
                o4.w = cen.w + rm4.z + ((((c + 3) & 63) != 63) ? rp1.x : 0.f);
                float4 rk = *(const float4*)&Lrnk[c];
                // ascending k (t asc, c asc) + strict > = first occurrence
                float v0 = o4.x * rk.x; if (v0 > bv) { bv = v0; ba = k0 + c + 0; }
                float v1 = o4.y * rk.y; if (v1 > bv) { bv = v1; ba = k0 + c + 1; }
                float v2 = o4.z * rk.z; if (v2 > bv) { bv = v2; ba = k0 + c + 2; }
                float v3 = o4.w * rk.w; if (v3 > bv) { bv = v3; ba = k0 + c + 3; }
                prevm = rm4;
                rpj = rp1;
            }
            bvr[h] = bv;
            bar[h] = ba;
        }
        __syncthreads();   // epilogue reads done before next tile stages
    }

    // ---- final cross-wave reduce (once): value-tie -> smaller index ----
#pragma unroll
    for (int h = 0; h < 2; ++h) {
        bvs[(qr << 6) + q_l] = bvr[h];
        bas[(qr << 6) + q_l] = bar[h];
        __syncthreads();
        if (tid < 64) {
            float v = bvs[tid];
            int a = bas[tid];
#pragma unroll
            for (int s = 1; s < 8; ++s) {
                float v2 = bvs[(s << 6) + tid];
                int a2 = bas[(s << 6) + tid];
                if (v2 > v || (v2 == v && a2 < a)) { v = v2; a = a2; }
            }
            int q = q0 + h * 64 + tid;
            part_val[(((b << 2) + kQ) << 12) + q] = v;
            part_arg[(((b << 2) + kQ) << 12) + q] = a;
        }
        __syncthreads();   // bvs/bas reusable for h=1
    }
}

// ---------------- gather + fold + inline 4-slot combine + S ------------------
// Per block (y, b, cg): combine the 4 k-slot partials (ascending kQ = ascending
// k -> first-occurrence argmax) for arg rows y-1..y+1; write S for row y
// (cg==0; rnq inline from pix2q); then T[c,y,x] = (1/9) sum_9 VT[a(q)+d][c].
__global__ __launch_bounds__(256)
void gatherT_kernel(const float* __restrict__ VT,
                    const float* __restrict__ part_val, const int* __restrict__ part_arg,
                    const float* __restrict__ pix2q,
                    float* __restrict__ S_out, float* __restrict__ T_out) {
    __shared__ int sArg[192];
    const int y = blockIdx.x, b = blockIdx.y, cg = blockIdx.z;
    const int tid = threadIdx.x;
    if (tid < 192) {
        int r = tid >> 6, x = tid & 63;
        int yy = y - 1 + r;
        int a = 0;
        if ((unsigned)yy < 64u) {
            int base = (b << 14) + (yy << 6) + x;   // part[(b*4+s)][q]
            float bv = -INFINITY; int ba = 0;
#pragma unroll
            for (int s = 0; s < 4; ++s) {    // ascending s = ascending k
                float v = part_val[base + (s << 12)];
                int aa = part_arg[base + (s << 12)];
                if (v > bv) { bv = v; ba = aa; }
            }
            a = ba;
            if (r == 1 && cg == 0) {         // S for row y, rnq inline
                float sq = 0.f;
                for (int dy = -1; dy <= 1; ++dy)
                    for (int dx = -1; dx <= 1; ++dx) {
                        int y2 = yy + dy, x2 = x + dx;
                        if ((unsigned)y2 < 64u && (unsigned)x2 < 64u)
                            sq += pix2q[(b << 12) + (y2 << 6) + x2];
                    }
                S_out[(b << 12) + (yy << 6) + x] =
                    bv * (1.f / fmaxf(sqrtf(sq), 1e-12f));
            }
        }
        sArg[tid] = a;
    }
    __syncthreads();

    const int x = tid >> 2, cq = tid & 3;
    const float* Vb = VT + (size_t)b * 4096 * 64 + cg * 16 + cq * 4;
    float ax = 0.f, ay = 0.f, az = 0.f, aw = 0.f;
#pragma unroll
    for (int t = 0; t < 9; ++t) {
        int dy = t / 3 - 1, dx = t % 3 - 1;
        int qy = y - dy, qx = x - dx;
        if ((unsigned)qy < 64u && (unsigned)qx < 64u) {
            int a = sArg[(1 - dy) * 64 + qx];
            int sy = (a >> 6) + dy, sx = (a & 63) + dx;
            if ((unsigned)sy < 64u && (unsigned)sx < 64u) {
                float4 v = *(const float4*)(Vb + (size_t)((sy << 6) + sx) * 64);
                ax += v.x; ay += v.y; az += v.z; aw += v.w;
            }
        }
    }
    float* Tb = T_out + ((size_t)b * 64 + cg * 16 + cq * 4) * HW + (y << 6) + x;
    Tb[0]          = ax * (1.f / 9.f);
    Tb[HW]         = ay * (1.f / 9.f);
    Tb[2 * HW]     = az * (1.f / 9.f);
    Tb[3 * HW]     = aw * (1.f / 9.f);
}

extern "C" void kernel_launch(void* const* d_in, const int* in_sizes, int n_in,
                              void* d_out, int out_size, void* d_ws, size_t ws_size,
                              hipStream_t stream) {
    const float* V = (const float*)d_in[0];
    const float* K = (const float*)d_in[1];
    const float* Q = (const float*)d_in[2];
    float* S_out = (float*)d_out;            // 4*4096
    float* T_out = S_out + 4 * HW;           // 4*64*4096

    char* ws = (char*)d_ws;
    float* pix2q = (float*)(ws + 0);                 // 64 KB
    float* pix2k = (float*)(ws + 65536);             // 64 KB
    float* part_val = (float*)(ws + 262144);         // 4*4*4096 f = 256 KB used
    int*   part_arg = (int*)(ws + 8650752);          // 256 KB used
    float* VT    = (float*)(ws + 10747904);          // 4*4096*64 f32 = 4 MiB
    unsigned short* Aq = (unsigned short*)(ws + 17039360);   // 4*4096*192 bf16 = 6 MiB
    unsigned short* Bq = (unsigned short*)(ws + 23330816);   // 6 MiB

    prep_kernel<<<dim3(64, 4, 3), 256, 0, stream>>>(Q, K, V, Aq, Bq, VT, pix2q, pix2k);
    gemm_fused_kernel<<<dim3(128, 4), 512, 0, stream>>>(Aq, Bq, pix2k, part_val, part_arg);
    gatherT_kernel<<<dim3(64, 4, 4), 256, 0, stream>>>(VT, part_val, part_arg, pix2q, S_out, T_out);
}

// Round 17
// 185.278 us; speedup vs baseline: 1.7614x; 1.7614x over previous
//
#include <hip/hip_runtime.h>
#include <math.h>

#define HW 4096   // H*W = 64*64; B=4, C=64, H=W=64, L=4096

typedef short bf16x8 __attribute__((ext_vector_type(8)));
typedef float floatx4 __attribute__((ext_vector_type(4)));
typedef unsigned short u16x8 __attribute__((ext_vector_type(8)));

__device__ __forceinline__ unsigned short f2bf_rne(float x) {
    unsigned int u = __float_as_uint(x);
    unsigned int r = (u + 0x7FFFu + ((u >> 16) & 1u)) >> 16;
    return (unsigned short)r;
}
__device__ __forceinline__ float bf2f(unsigned short h) {
    return __uint_as_float(((unsigned int)h) << 16);
}

// async global->LDS, 16 B per lane; LDS dest is wave-uniform base + lane*16.
__device__ __forceinline__ void gload_lds16(const void* gptr, void* lptr) {
    auto g = (const __attribute__((address_space(1))) unsigned int*)(unsigned long long)(gptr);
    auto l = (__attribute__((address_space(3))) unsigned int*)(unsigned int)(unsigned long long)(lptr);
    __builtin_amdgcn_global_load_lds(g, l, 16, 0, 0);
}

// ---------------- prep: z=0 Q / z=1 K: split fp32 -> bf16 (hi,lo), transpose
// to [p][c], fused per-pixel squared norms. Row layout (192 shorts):
//   Aq[b][p] = [Qh | UNINIT | Ql],  Bq[b][p] = [Kh | Kl | UNINIT]
// (readers use only A slices {0,2} / B slices {0,1}).
// z=2: transpose V -> VT[b][p][c] (f32) so gatherT reads channels contiguous.
__global__ __launch_bounds__(256)
void prep_kernel(const float* __restrict__ Q, const float* __restrict__ K,
                 const float* __restrict__ V,
                 unsigned short* __restrict__ Aq, unsigned short* __restrict__ Bq,
                 float* __restrict__ VT,
                 float* __restrict__ pix2q, float* __restrict__ pix2k) {
    __shared__ float sT[64][65];
    const int tid = threadIdx.x;
    const int p0 = blockIdx.x * 64;
    const int b = blockIdx.y;
    const int which = blockIdx.z;            // 0=Q, 1=K, 2=V
    const float* __restrict__ src = (which == 0) ? Q : ((which == 1) ? K : V);

#pragma unroll
    for (int it = 0; it < 16; ++it) {
        int idx = it * 256 + tid;
        int c = idx >> 6, x = idx & 63;
        sT[c][x] = src[((size_t)b * 64 + c) * HW + p0 + x];
    }
    __syncthreads();
    const int pp = tid >> 2, qt = tid & 3;

    if (which == 2) {                        // V: pure f32 transpose
        float* dst = VT + ((size_t)b * 4096 + p0 + pp) * 64 + qt * 16;
#pragma unroll
        for (int j = 0; j < 4; ++j) {
            float4 v = make_float4(sT[qt * 16 + 4 * j + 0][pp], sT[qt * 16 + 4 * j + 1][pp],
                                   sT[qt * 16 + 4 * j + 2][pp], sT[qt * 16 + 4 * j + 3][pp]);
            *(float4*)(dst + 4 * j) = v;
        }
        return;
    }

    const int isK = which;
    unsigned short* __restrict__ dst = isK ? Bq : Aq;
    float* __restrict__ pix2 = isK ? pix2k : pix2q;
    const size_t base = ((size_t)b * 4096 + p0 + pp) * 192;
    {
        float sq = 0.f;
        u16x8 hv[2], lv[2];
#pragma unroll
        for (int g = 0; g < 2; ++g)
#pragma unroll
            for (int j = 0; j < 8; ++j) {
                int c = qt * 16 + g * 8 + j;
                float x = sT[c][pp];
                sq = fmaf(x, x, sq);
                unsigned short h = f2bf_rne(x);
                hv[g][j] = h;
                lv[g][j] = f2bf_rne(x - bf2f(h));
            }
        sq += __shfl_xor(sq, 1, 64);
        sq += __shfl_xor(sq, 2, 64);
        if (qt == 0) pix2[(b << 12) + p0 + pp] = sq;
#pragma unroll
        for (int g = 0; g < 2; ++g) {
            int co = qt * 16 + g * 8;
            *(u16x8*)(dst + base + co)                     = hv[g];  // hi slice
            *(u16x8*)(dst + base + (isK ? 64 : 128) + co)  = lv[g];  // lo slice
        }
    }
}

// ---------------- fused MFMA GEMM (K=576: y-3sum in K) + x-3sum + argmax -----
// 128x128 tile, 8 waves (512 thr), wave tile 64(q) x 32(k): acc = 32 regs.
// 3 mega-steps (one per dy); per kk: all 12 frag ds_reads issue UP FRONT
// (first MM8 gated on its 6 via lgkmcnt; the rest arrive under MFMA), then
// s0=Qh.Kh, s1=Qh.Kl, s2=Ql.Kh with distinct temp arrays (no false deps);
// kk fully unrolled so the pressure-aware scheduler overlaps kk1 loads with
// kk0 MFMAs up to the 128-reg cap. Kh'/Al-unused never staged.
// Rings: A 5 slots {Ah0@0,Ah1@1,Ah2@4,Ah3@2; Al0@2,Al1@3,Al2@0,Al3@3},
//        B 5 slots {Bh0@0,Bh1@1,Bh2@4,Bh3@2; Bl0@2,Bl1@3,Bl2@0,Bl3@3}.
// Counted-vmcnt ring schedule hand-verified (R12); the 9 early pix2k loads
// are OLDER than all gloads so every counted wait also retires them.
// [Template ceiling note, R14-R16: LDS-traffic cut, 32x32 MFMA, k-batching
//  all falsified -- this config (R13) is the measured optimum of the
//  2-barrier 128^2 family; deeper pipelining spills under hipcc.]
#define WAITV(n_) asm volatile("s_waitcnt vmcnt(" #n_ ")" ::: "memory")
#define PBAR(n_) do { WAITV(n_); __builtin_amdgcn_s_barrier(); \
                      asm volatile("" ::: "memory"); } while (0)
#define SB do { __builtin_amdgcn_s_barrier(); asm volatile("" ::: "memory"); } while (0)

#define ISSUE_A(c_, sg_, slot_) \
    gload_lds16(agb + (size_t)((c_) * 64 + rr) * 384 + (sg_) * 128 + G16, \
                smem + (slot_) * 8192 + t16)
#define ISSUE_B(c_, sg_, slot_) \
    gload_lds16(bgb + (size_t)((c_) * 64 + rr) * 384 + (sg_) * 128 + G16, \
                smemB + (slot_) * 8192 + t16)

#define GISS_A(c_, sg_, slot_) do { \
    uint4 v_ = make_uint4(0u, 0u, 0u, 0u); \
    if ((unsigned)(arow + (c_) * 64 + rr) < 4096u) \
        v_ = *(const uint4*)(agb + (ptrdiff_t)((c_) * 64 + rr) * 384 + (sg_) * 128 + G16); \
    *(uint4*)(smem + (slot_) * 8192 + t16) = v_; \
} while (0)
#define GISS_B(c_, sg_, slot_) do { \
    uint4 v_ = make_uint4(0u, 0u, 0u, 0u); \
    if ((unsigned)(brow + (c_) * 64 + rr) < 4096u) \
        v_ = *(const uint4*)(bgb + (ptrdiff_t)((c_) * 64 + rr) * 384 + (sg_) * 128 + G16); \
    *(uint4*)(smemB + (slot_) * 8192 + t16) = v_; \
} while (0)

#define MM8(af_, bf_) do { \
    _Pragma("unroll") \
    for (int mt_ = 0; mt_ < 4; ++mt_) \
        _Pragma("unroll") \
        for (int nt_ = 0; nt_ < 2; ++nt_) \
            acc[mt_][nt_] = __builtin_amdgcn_mfma_f32_16x16x32_bf16( \
                (af_)[mt_], (bf_)[nt_], acc[mt_][nt_], 0, 0, 0); \
} while (0)

#define DY_MEGA(dy_) do { \
    const char* AhS_ = smem + ahS[wm + (dy_)] * 8192 + rowB; \
    const char* AlS_ = smem + alS[wm + (dy_)] * 8192 + rowB; \
    const char* BhS_ = smemB + bhS[wnC + (dy_)] * 8192 + rowBB; \
    const char* BlS_ = smemB + blS[wnC + (dy_)] * 8192 + rowBB; \
    _Pragma("unroll") \
    for (int kk = 0; kk < 2; ++kk) { \
        const int pk_ = kk ? posK1 : posK0; \
        bf16x8 afc[4], bfc[2], bl2[2], al4[4]; \
        _Pragma("unroll") \
        for (int mt = 0; mt < 4; ++mt) \
            afc[mt] = *(const bf16x8*)(AhS_ + mt * 2048 + pk_); \
        _Pragma("unroll") \
        for (int nt = 0; nt < 2; ++nt) \
            bfc[nt] = *(const bf16x8*)(BhS_ + nt * 2048 + pk_); \
        _Pragma("unroll") \
        for (int nt = 0; nt < 2; ++nt) \
            bl2[nt] = *(const bf16x8*)(BlS_ + nt * 2048 + pk_); \
        _Pragma("unroll") \
        for (int mt = 0; mt < 4; ++mt) \
            al4[mt] = *(const bf16x8*)(AlS_ + mt * 2048 + pk_); \
        __builtin_amdgcn_s_setprio(1); \
        MM8(afc, bfc); \
        MM8(afc, bl2); \
        MM8(al4, bfc); \
        __builtin_amdgcn_s_setprio(0); \
    } \
} while (0)

__global__ __launch_bounds__(512, 4)
void gemm_fused_kernel(const unsigned short* __restrict__ Aq, const unsigned short* __restrict__ Bq,
                       const float* __restrict__ pix2k,
                       float* __restrict__ part_val, int* __restrict__ part_arg) {
    __shared__ __align__(16) char smem[81920];   // A 5x8K | B 5x8K; epilogue aliases A region
    char* const smemB = smem + 40960;
    const int tid = threadIdx.x;
    const int lane = tid & 63, wid = tid >> 6;
    const int m15 = lane & 15, quad = lane >> 4;
    const int wm = wid & 1;                  // q half (64 rows)
    const int wn2 = wid >> 1;                // k quarter (32 cols), 0..3
    const int wnC = wn2 >> 1, wnF = wn2 & 1; // B chunk half / frag pair
    // chunk -> slot maps (see header comment)
    const int ahS[4] = {0, 1, 4, 2};
    const int alS[4] = {2, 3, 0, 3};
    const int bhS[4] = {0, 1, 4, 2};
    const int blS[4] = {2, 3, 0, 3};
    // XCD-chunked swizzle: per-b 1024 wgs; XCD x owns 4 q-tiles x 32 k-tiles.
    const int f = blockIdx.x + (blockIdx.y << 5);
    const int o = ((f & 7) << 7) + (f >> 3);
    const int kt = o & 31, qt = o >> 5;
    const int k0 = kt << 7;
    const int q0 = qt << 7;
    const int b = blockIdx.z;
    const int arow = q0 - 64, brow = k0 - 64;
    const char* agb = (const char*)(Aq + (size_t)b * 4096 * 192) + (ptrdiff_t)arow * 384;
    const char* bgb = (const char*)(Bq + (size_t)b * 4096 * 192) + (ptrdiff_t)brow * 384;
    const bool aInt = (q0 >= 64) && (q0 <= 4096 - 192);
    const bool bInt = (k0 >= 64) && (k0 <= 4096 - 192);

    // staging: 512 thr x 16 B = one 8 KB chunk per issue (1 gload/thread)
    const int rr = tid >> 3;
    const int G16 = ((tid & 7) ^ (rr & 7)) * 16;
    const int t16 = tid * 16;
    // fragment-read offsets (row&7 == m15&7 for all frag rows)
    const int rowB = m15 * 128;
    const int rowBB = (wnF * 32 + m15) * 128;
    const int posK0 = (quad ^ (m15 & 7)) * 16;
    const int posK1 = ((4 + quad) ^ (m15 & 7)) * 16;

    // early rnk inputs: 9 pix2k loads issued BEFORE staging; results unused
    // until the epilogue, so no wait here; being oldest, all counted waits
    // retire them (waves without loads just count fewer -- both safe).
    float pk9[9];
    if (tid < 128) {
        int k = k0 + tid;
        int py = k >> 6, px = k & 63;
#pragma unroll
        for (int t = 0; t < 9; ++t) {
            int yy = py + t / 3 - 1, xx = px + t % 3 - 1;
            pk9[t] = ((unsigned)yy < 64u && (unsigned)xx < 64u)
                   ? pix2k[(b << 12) + (yy << 6) + xx] : 0.f;
        }
    } else {
#pragma unroll
        for (int t = 0; t < 9; ++t) pk9[t] = 0.f;
    }

    floatx4 acc[4][2];
#pragma unroll
    for (int i = 0; i < 4; ++i)
#pragma unroll
        for (int j = 0; j < 2; ++j) acc[i][j] = (floatx4)0.f;

    if (aInt && bInt) {
        // prologue (10 chunks): Ah0@0 Ah1@1 Bh0@0 Bh1@1 Al0@2 Al1@3 Bl0@2
        // Bl1@3 Ah2@4 Bh2@4
        ISSUE_A(0, 0, 0); ISSUE_A(1, 0, 1); ISSUE_B(0, 0, 0); ISSUE_B(1, 0, 1);
        ISSUE_A(0, 2, 2); ISSUE_A(1, 2, 3); ISSUE_B(0, 1, 2); ISSUE_B(1, 1, 3);
        ISSUE_A(2, 0, 4); ISSUE_B(2, 0, 4);
        PBAR(2);                 // retire first 8 = dy0 working set (+ pix2k)
        DY_MEGA(0);
        SB;                      // dy0 readers done -> slots 0(A),0(B),2(A),2(B) free
        ISSUE_A(2, 2, 0);        // Al2 -> A slot 0
        ISSUE_B(2, 1, 0);        // Bl2 -> B slot 0
        ISSUE_A(3, 0, 2);        // Ah3 -> A slot 2
        ISSUE_B(3, 0, 2);        // Bh3 -> B slot 2
        PBAR(2);                 // retire Ah2,Bh2,Al2,Bl2 (Ah3,Bh3 in flight)
        DY_MEGA(1);
        SB;                      // dy1 readers done -> slots 3(A),3(B) free
        ISSUE_A(3, 2, 3);        // Al3 -> A slot 3
        ISSUE_B(3, 1, 3);        // Bl3 -> B slot 3
        PBAR(0);                 // retire Ah3,Bh3,Al3,Bl3
        DY_MEGA(2);
    } else {
        // guarded boundary path: same slots, predicated uint4 + ds_write
        GISS_A(0, 0, 0); GISS_A(1, 0, 1); GISS_B(0, 0, 0); GISS_B(1, 0, 1);
        GISS_A(0, 2, 2); GISS_A(1, 2, 3); GISS_B(0, 1, 2); GISS_B(1, 1, 3);
        GISS_A(2, 0, 4); GISS_B(2, 0, 4);
        __syncthreads();
        DY_MEGA(0);
        __syncthreads();
        GISS_A(2, 2, 0); GISS_B(2, 1, 0); GISS_A(3, 0, 2); GISS_B(3, 0, 2);
        __syncthreads();
        DY_MEGA(1);
        __syncthreads();
        GISS_A(3, 2, 3); GISS_B(3, 1, 3);
        __syncthreads();
        DY_MEGA(2);
    }
    __syncthreads();   // rings dead before epilogue overwrites

    // ---- epilogue: Lrnk from preloaded pk9 (pure ALU); two 64-row phases;
    // x-3sum + argmax over the 128-k tile; cross-wave LDS reduce -> one
    // partial per (block, q) ----
    float* Csh = (float*)smem;               // [64][133] = 34048 B
    float* bvs = (float*)(smem + 34816);     // [8][64]
    int*   bas = (int*)(smem + 36864);       // [8][64]
    float* Lrnk = (float*)(smem + 38912);    // [128]
    if (tid < 128) {
        float sk = 0.f;
#pragma unroll
        for (int t = 0; t < 9; ++t) sk += pk9[t];
        Lrnk[tid] = 1.f / fmaxf(sqrtf(sk), 1e-12f);
    }
    const int q_l = tid & 63;
    const int qr = tid >> 6;                 // k-eighth (0..7), one per wave
    const int c0 = qr * 16;
    const float4 zero4 = make_float4(0.f, 0.f, 0.f, 0.f);

#pragma unroll
    for (int h = 0; h < 2; ++h) {
        if (h) __syncthreads();              // phase-0 readers done before overwrite
        if (wm == h) {
#pragma unroll
            for (int mt = 0; mt < 4; ++mt)
#pragma unroll
                for (int nt = 0; nt < 2; ++nt)
#pragma unroll
                    for (int j = 0; j < 4; ++j)
                        Csh[(mt * 16 + quad * 4 + j) * 133 + (wn2 << 5) + nt * 16 + m15] =
                            acc[mt][nt][j];
        }
        __syncthreads();                     // also orders Lrnk writes (h==0)

        const bool qm = q_l > 0;             // qx>0: diag- allowed
        const bool qp = q_l < 63;            // qx<63: diag+ allowed
        const float* rC = Csh + q_l * 133;
        const float* rM = Csh + (q_l - 1) * 133;
        const float* rP = Csh + (q_l + 1) * 133;
        float4 prevm = (qm && c0 > 0) ? *(const float4*)&rM[c0 - 4] : zero4;
        float4 rpj   = qp ? *(const float4*)&rP[c0] : zero4;
        float bv = -INFINITY;
        int ba = 0;
#pragma unroll
        for (int j = 0; j < 4; ++j) {
            int c = c0 + 4 * j;
            float4 cen = *(const float4*)&rC[c];
            float4 rm4 = qm ? *(const float4*)&rM[c] : zero4;
            float4 rp1 = (qp && (c + 4) < 128) ? *(const float4*)&rP[c + 4] : zero4;
            float4 o4;
            o4.x = cen.x + (((c & 63) != 0) ? prevm.w : 0.f) + rpj.y;
            o4.y = cen.y + rm4.x + rpj.z;
            o4.z = cen.z + rm4.y + rpj.w;
            o4.w = cen.w + rm4.z + ((((c + 3) & 63) != 63) ? rp1.x : 0.f);
            float4 rk = *(const float4*)&Lrnk[c];
            // ascending k + strict > = first-occurrence argmax
            float v0 = o4.x * rk.x; if (v0 > bv) { bv = v0; ba = k0 + c + 0; }
            float v1 = o4.y * rk.y; if (v1 > bv) { bv = v1; ba = k0 + c + 1; }
            float v2 = o4.z * rk.z; if (v2 > bv) { bv = v2; ba = k0 + c + 2; }
            float v3 = o4.w * rk.w; if (v3 > bv) { bv = v3; ba = k0 + c + 3; }
            prevm = rm4;
            rpj = rp1;
        }
        bvs[(qr << 6) + q_l] = bv;
        bas[(qr << 6) + q_l] = ba;
        __syncthreads();
        if (tid < 64) {
            float v = bvs[tid];
            int a = bas[tid];
#pragma unroll
            for (int s = 1; s < 8; ++s) {    // ascending eighth = ascending k
                float v2 = bvs[(s << 6) + tid];
                if (v2 > v) { v = v2; a = bas[(s << 6) + tid]; }
            }
            int q = q0 + h * 64 + tid;
            part_val[(((b << 5) + kt) << 12) + q] = v;
            part_arg[(((b << 5) + kt) << 12) + q] = a;
        }
    }
}

// ---------------- combine 32 k-slot partials -> final arg + S ----------------
__global__ __launch_bounds__(256)
void argcombine_kernel(const float* __restrict__ part_val, const int* __restrict__ part_arg,
                       const float* __restrict__ pix2q,
                       float* __restrict__ S_out, int* __restrict__ argF) {
    __shared__ float rv[4][64];
    __shared__ int ra[4][64];
    const int tid = threadIdx.x;
    const int qi = tid & 63, sg = tid >> 6;
    const int q = blockIdx.x * 64 + qi;
    const int b = blockIdx.y;
    const int base = (b << 17) + q;
    float bv = -INFINITY; int ba = 0;
#pragma unroll
    for (int i = 0; i < 8; ++i) {            // ascending s = ascending k
        int s = sg * 8 + i;
        float v = part_val[base + (s << 12)];
        int aa = part_arg[base + (s << 12)];
        if (v > bv) { bv = v; ba = aa; }
    }
    rv[sg][qi] = bv; ra[sg][qi] = ba;
    __syncthreads();
    if (tid < 64) {
        float v = rv[0][tid]; int a = ra[0][tid];
#pragma unroll
        for (int s = 1; s < 4; ++s) {        // ascending group: first max wins
            float v2 = rv[s][tid];
            if (v2 > v) { v = v2; a = ra[s][tid]; }
        }
        int py = blockIdx.x, px = tid;       // q = py*64 + px
        float sq = 0.f;
        for (int dy = -1; dy <= 1; ++dy)
            for (int dx = -1; dx <= 1; ++dx) {
                int y2 = py + dy, x2 = px + dx;
                if ((unsigned)y2 < 64u && (unsigned)x2 < 64u)
                    sq += pix2q[(b << 12) + (y2 << 6) + x2];
            }
        int idx = (b << 12) + (py << 6) + px;
        S_out[idx] = v * (1.f / fmaxf(sqrtf(sq), 1e-12f));
        argF[idx] = a;
    }
}

// ---------------- gather + fold: T[c,y,x] = (1/9) sum_9 VT[a(q)+d][c] --------
__global__ __launch_bounds__(256)
void gatherT_kernel(const float* __restrict__ VT, const int* __restrict__ argF,
                    float* __restrict__ T_out) {
    __shared__ int sArg[192];
    const int y = blockIdx.x, b = blockIdx.y, cg = blockIdx.z;
    const int tid = threadIdx.x;
    if (tid < 192) {
        int r = tid >> 6, x = tid & 63;
        int yy = y - 1 + r;
        sArg[tid] = ((unsigned)yy < 64u) ? argF[(b << 12) + (yy << 6) + x] : 0;
    }
    __syncthreads();

    const int x = tid >> 2, cq = tid & 3;
    const float* Vb = VT + (size_t)b * 4096 * 64 + cg * 16 + cq * 4;
    float ax = 0.f, ay = 0.f, az = 0.f, aw = 0.f;
#pragma unroll
    for (int t = 0; t < 9; ++t) {
        int dy = t / 3 - 1, dx = t % 3 - 1;
        int qy = y - dy, qx = x - dx;
        if ((unsigned)qy < 64u && (unsigned)qx < 64u) {
            int a = sArg[(1 - dy) * 64 + qx];
            int sy = (a >> 6) + dy, sx = (a & 63) + dx;
            if ((unsigned)sy < 64u && (unsigned)sx < 64u) {
                float4 v = *(const float4*)(Vb + (size_t)((sy << 6) + sx) * 64);
                ax += v.x; ay += v.y; az += v.z; aw += v.w;
            }
        }
    }
    float* Tb = T_out + ((size_t)b * 64 + cg * 16 + cq * 4) * HW + (y << 6) + x;
    Tb[0]          = ax * (1.f / 9.f);
    Tb[HW]         = ay * (1.f / 9.f);
    Tb[2 * HW]     = az * (1.f / 9.f);
    Tb[3 * HW]     = aw * (1.f / 9.f);
}

extern "C" void kernel_launch(void* const* d_in, const int* in_sizes, int n_in,
                              void* d_out, int out_size, void* d_ws, size_t ws_size,
                              hipStream_t stream) {
    const float* V = (const float*)d_in[0];
    const float* K = (const float*)d_in[1];
    const float* Q = (const float*)d_in[2];
    float* S_out = (float*)d_out;            // 4*4096
    float* T_out = S_out + 4 * HW;           // 4*64*4096

    char* ws = (char*)d_ws;
    float* pix2q = (float*)(ws + 0);                 // 64 KB
    float* pix2k = (float*)(ws + 65536);             // 64 KB
    float* part_val = (float*)(ws + 262144);         // 4*32*4096 f = 2 MB used
    int*   argF  = (int*)(ws + 4456448);             // 64 KB
    int*   part_arg = (int*)(ws + 8650752);          // 2 MB used
    float* VT    = (float*)(ws + 10747904);          // 4*4096*64 f32 = 4 MiB
    unsigned short* Aq = (unsigned short*)(ws + 17039360);   // 4*4096*192 bf16 = 6 MiB
    unsigned short* Bq = (unsigned short*)(ws + 23330816);   // 6 MiB

    prep_kernel<<<dim3(64, 4, 3), 256, 0, stream>>>(Q, K, V, Aq, Bq, VT, pix2q, pix2k);
    gemm_fused_kernel<<<dim3(32, 32, 4), 512, 0, stream>>>(Aq, Bq, pix2k, part_val, part_arg);
    argcombine_kernel<<<dim3(64, 4), 256, 0, stream>>>(part_val, part_arg, pix2q, S_out, argF);
    gatherT_kernel<<<dim3(64, 4, 4), 256, 0, stream>>>(VT, argF, T_out);
}